// Round 9
// baseline (9041.267 us; speedup 1.0000x reference)
//
#include <hip/hip_runtime.h>
#include <stdint.h>

// Teacher-forced LSTM, B=64 T=512 D=H=1024.
// gates(t) = m(t)*(h@Wx^T) + (1-m(t))*(x(t)@Wx^T) + h@Wh^T + bias,  h = h(t-1)
// x(t)@Wx^T is computed in the PREVIOUS step's barrier-wait slack (x is known
// ahead); critical path per step = h exchange + 32 MFMAs + epilogue + cell.
// Persistent: 128 blocks x 512 thr; block owns 8 hidden units (32 gate rows).
// Weights bf16 LDS-stationary, conflict-free layout. 32x32x16 MFMA;
// 8 waves = 2 M-tiles(32 batches) x 4 K-quarters(256 k).
// h exchange: ROT=1 -> ROTATING buffers hrot[t][b][u] (64MB ws). Producers
// store agent-scope write-through; consumers use PLAIN CACHED loads -- safe
// because each address is written once per launch and read only after the
// flag (no address reuse -> no stale lines; one acquire-agent fence at kernel
// start flushes poison/previous-launch lines). 16 blocks/XCD share one L2
// fill of the 128KB panel. ROT=0 fallback: 2 slots + atomic loads (R5-proven).
// Barrier: per-block flag -> block-0 master polls -> single gen word (R5).

#define B_ 64
#define T_ 512
#define D_ 1024
#define H_ 1024
#define NBLK 128
#define UPB 8
#define NROW 32
#define NTHR 512

typedef __attribute__((ext_vector_type(8))) short short8;
typedef __attribute__((ext_vector_type(16))) float f32x16;

// LDS (bytes): Wx 64KB @0 | Wh 64KB @65536 | gbuf f32[2][64][33] @131072 |
// m_lds f32[2][64] @147968 | bias f32[32] @148480
#define GBUF_OFF 131072
#define MLDS_OFF 147968
#define BIAS_OFF 148480
#define SMEM_BYTES 148608

// ws (bytes): flags[128] u32 @0 | gen u32 @2048 | hrot @8192:
//   ROT=1: [512][64 b][1024 u] bf16 (64MB)   ROT=0: [2][64][1024] bf16
#define WS_HROT 8192
#define HSLOT 65536 /* shorts per h slot (131072 B) */

__device__ __forceinline__ unsigned f2bf(float f) {  // fp32 -> bf16 RNE
  unsigned u = __float_as_uint(f);
  return (u + 0x7FFFu + ((u >> 16) & 1u)) >> 16;
}
__device__ __forceinline__ float sigf(float x) { return 1.0f / (1.0f + __expf(-x)); }
__device__ __forceinline__ float tanhf_(float x) { return 1.0f - 2.0f / (__expf(2.0f * x) + 1.0f); }

template<int ROT>
__global__ __launch_bounds__(NTHR, 1)
void lstm_persist(const float* __restrict__ xf,
                  const float* __restrict__ tm,
                  const float* __restrict__ Wx, const float* __restrict__ bxp,
                  const float* __restrict__ Wh, const float* __restrict__ bhp,
                  float* __restrict__ out,
                  unsigned short* __restrict__ hrot,
                  unsigned* __restrict__ flags,
                  unsigned* __restrict__ gen)
{
  extern __shared__ char smem[];
  float* gbuf     = (float*)(smem + GBUF_OFF);  // [2][64][33]
  float* m_lds    = (float*)(smem + MLDS_OFF);  // [2][64]
  float* bias_lds = (float*)(smem + BIAS_OFF);

  const int tid = threadIdx.x;
  const int bid = blockIdx.x;

  // ---- stage Wx,Wh -> LDS, conflict-free layout ----
  // dword slot s in [0,16384): dw=s&3, n=(s>>2)&31, kg=(s>>7)&1, j=(s>>8)&15, kq=s>>12
  // byte = s*4 = kq*16384 + j*1024 + kg*512 + n*16 + dw*4 ; k = kq*256+j*16+kg*8+dw*2
  for (int i = 0; i < 32; ++i) {
    const int s  = i * NTHR + tid;
    const int dw = s & 3, n = (s >> 2) & 31, kgs = (s >> 7) & 1;
    const int js = (s >> 8) & 15, kqs = s >> 12;
    const int grow = (n >> 3) * H_ + bid * UPB + (n & 7);
    const int k = kqs * 256 + js * 16 + kgs * 8 + dw * 2;
    float2 v = *(const float2*)(Wx + (size_t)grow * D_ + k);
    *(unsigned*)(smem + (size_t)s * 4) = f2bf(v.x) | (f2bf(v.y) << 16);
    v = *(const float2*)(Wh + (size_t)grow * H_ + k);
    *(unsigned*)(smem + 65536 + (size_t)s * 4) = f2bf(v.x) | (f2bf(v.y) << 16);
  }
  if (tid < NROW) {
    const int grow = (tid >> 3) * H_ + bid * UPB + (tid & 7);
    bias_lds[tid] = bxp[grow] + bhp[grow];
  }

  // one-time L2/L1 invalidate: flush poison / previous-launch lines so that
  // plain cached loads of hrot are fresh-by-first-touch for this launch.
  if (ROT) __builtin_amdgcn_fence(__ATOMIC_ACQUIRE, "agent");

  const int lane = tid & 63;
  const int wid  = tid >> 6;   // 0..7
  const int mt   = wid >> 2;   // M-tile (32 batch rows)
  const int kq   = wid & 3;    // K-quarter of 1024 (256 each)
  const int l31  = lane & 31;  // A: batch row in tile / B: gate row
  const int kg   = lane >> 5;  // 0..1 (k-half of 16)
  const int m0   = mt * 32;

  const unsigned wxbase = (unsigned)(kq * 16384 + kg * 512 + l31 * 16);
  const unsigned whbase = 65536 + wxbase;
#define LWX(J) (*(const short8*)(smem + wxbase + (unsigned)((J) * 1024)))
#define LWH(J) (*(const short8*)(smem + whbase + (unsigned)((J) * 1024)))

  const int cb = tid >> 3;       // cell: batch (0..63)
  const int cu = tid & 7;        // cell: unit within block
  const int hu = bid * UPB + cu; // global hidden unit
  float ccell = 0.0f, hv = 0.0f;

  __syncthreads();

  // ---- preamble: accB(0) = x(0)@Wx^T ; m(0) -> m_lds slot 0 ----
  f32x16 accB = {0,0,0,0,0,0,0,0,0,0,0,0,0,0,0,0};
  {
    const float* xp = xf + (size_t)(m0 + l31) * T_ * D_ + (unsigned)(kq * 256 + kg * 8);
#pragma unroll
    for (int j = 0; j < 16; ++j) {
      float4 a0 = *(const float4*)(xp + j * 16);
      float4 a1 = *(const float4*)(xp + j * 16 + 4);
      short8 r;
      r[0] = (short)f2bf(a0.x); r[1] = (short)f2bf(a0.y);
      r[2] = (short)f2bf(a0.z); r[3] = (short)f2bf(a0.w);
      r[4] = (short)f2bf(a1.x); r[5] = (short)f2bf(a1.y);
      r[6] = (short)f2bf(a1.z); r[7] = (short)f2bf(a1.w);
      accB = __builtin_amdgcn_mfma_f32_32x32x16_bf16(r, LWX(j), accB, 0, 0, 0);
    }
    if (tid < B_) m_lds[tid] = tm[tid * T_];
  }

  for (int t = 0; t < T_; ++t) {
    const unsigned tgt = (unsigned)(t + 1);
    const int nxt = (t + 1 < T_) ? (t + 1) : t;

    // ---- critical path: h(t-1) frags (slot t) -> 32 MFMAs ----
    const unsigned short* hp =
        hrot + (size_t)(ROT ? t : (t & 1)) * HSLOT +
        (size_t)(m0 + l31) * 1024 + (unsigned)(kq * 256 + kg * 8);
    short8 hfrag[16];
    if (ROT) {
#pragma unroll
      for (int j = 0; j < 16; ++j) hfrag[j] = *(const short8*)(hp + j * 16);
    } else {
#pragma unroll
      for (int j = 0; j < 16; ++j) {
        unsigned long long lo = __hip_atomic_load(
            (const unsigned long long*)hp + j * 4,
            __ATOMIC_RELAXED, __HIP_MEMORY_SCOPE_AGENT);
        unsigned long long hi = __hip_atomic_load(
            (const unsigned long long*)hp + j * 4 + 1,
            __ATOMIC_RELAXED, __HIP_MEMORY_SCOPE_AGENT);
        ((unsigned long long*)&hfrag[j])[0] = lo;
        ((unsigned long long*)&hfrag[j])[1] = hi;
      }
    }
    f32x16 accA = {0,0,0,0,0,0,0,0,0,0,0,0,0,0,0,0};  // h@Wx^T
    f32x16 accC = {0,0,0,0,0,0,0,0,0,0,0,0,0,0,0,0};  // h@Wh^T
#pragma unroll
    for (int j = 0; j < 16; ++j) {
      accA = __builtin_amdgcn_mfma_f32_32x32x16_bf16(hfrag[j], LWX(j), accA, 0, 0, 0);
      accC = __builtin_amdgcn_mfma_f32_32x32x16_bf16(hfrag[j], LWH(j), accC, 0, 0, 0);
    }

    // ---- epilogue: g = m*accA + (1-m)*accB + accC (+bias), 2-slab reduce ----
    // C layout (32x32): col = lane&31 (gate row), row = (e&3)+8*(e>>2)+4*kg (batch)
    const float* ml = m_lds + (t & 1) * B_;
    const int s = kq >> 1;
    if ((kq & 1) == 0) {
#pragma unroll
      for (int e = 0; e < 16; ++e) {
        const int br = m0 + (e & 3) + 8 * (e >> 2) + 4 * kg;
        const float mv = ml[br];
        float g = mv * accA[e] + (1.0f - mv) * accB[e] + accC[e];
        if (kq == 0) g += bias_lds[l31];
        gbuf[(s * 64 + br) * 33 + l31] = g;
      }
    }
    __syncthreads();  // (B)
    if (kq & 1) {
#pragma unroll
      for (int e = 0; e < 16; ++e) {
        const int br = m0 + (e & 3) + 8 * (e >> 2) + 4 * kg;
        const float mv = ml[br];
        gbuf[(s * 64 + br) * 33 + l31] += mv * accA[e] + (1.0f - mv) * accB[e] + accC[e];
      }
    }
    __syncthreads();  // (C)

    // ---- cell: one (b,u) per thread; h store agent write-through ----
    {
      const float* g0 = gbuf + cb * 33;
      const float* g1 = gbuf + (64 + cb) * 33;
      const float gi = g0[cu]      + g1[cu];
      const float gf = g0[8 + cu]  + g1[8 + cu];
      const float gg = g0[16 + cu] + g1[16 + cu];
      const float go = g0[24 + cu] + g1[24 + cu];
      const float iv = sigf(gi), fv = sigf(gf), gv = tanhf_(gg), ov = sigf(go);
      ccell = ccell * fv + iv * gv;
      hv = ov * tanhf_(ccell);
      if (!ROT || (t + 1 < T_)) {
        unsigned short* dst = hrot +
            (size_t)(ROT ? (t + 1) : ((t + 1) & 1)) * HSLOT + (size_t)cb * 1024 + hu;
        __hip_atomic_store(dst, (unsigned short)f2bf(hv),
                           __ATOMIC_RELAXED, __HIP_MEMORY_SCOPE_AGENT);
      }
    }

    __syncthreads();  // (D) drains h stores (vmcnt(0) before s_barrier)

    if (bid == 0) {  // master: poll + publish gen ASAP
      if (wid == 0) {
        const int i0 = 1 + lane;   // 1..64
        const int i1 = 65 + lane;  // 65..127 valid
        for (;;) {
          unsigned v0 = __hip_atomic_load(flags + i0,
                                          __ATOMIC_RELAXED, __HIP_MEMORY_SCOPE_AGENT);
          unsigned v1 = (i1 < NBLK)
                          ? __hip_atomic_load(flags + i1,
                                              __ATOMIC_RELAXED, __HIP_MEMORY_SCOPE_AGENT)
                          : tgt;
          if (__all((v0 >= tgt) && (v1 >= tgt))) break;
          __builtin_amdgcn_s_sleep(1);
        }
        if (lane == 0)
          __hip_atomic_store(gen, tgt, __ATOMIC_RELAXED, __HIP_MEMORY_SCOPE_AGENT);
      }
    } else {
      if (tid == 0)
        __hip_atomic_store(flags + bid, tgt,
                           __ATOMIC_RELAXED, __HIP_MEMORY_SCOPE_AGENT);
    }

    // ---- slack zone (overlaps gen wait): out store, x(t+1)@Wx, m(t+1) ----
    out[((size_t)cb * T_ + t) * H_ + hu] = hv;
    f32x16 accBn = {0,0,0,0,0,0,0,0,0,0,0,0,0,0,0,0};
    {
      const float* xp = xf + ((size_t)(m0 + l31) * T_ + nxt) * D_ +
                        (unsigned)(kq * 256 + kg * 8);
#pragma unroll
      for (int j = 0; j < 16; ++j) {
        float4 a0 = *(const float4*)(xp + j * 16);
        float4 a1 = *(const float4*)(xp + j * 16 + 4);
        short8 r;
        r[0] = (short)f2bf(a0.x); r[1] = (short)f2bf(a0.y);
        r[2] = (short)f2bf(a0.z); r[3] = (short)f2bf(a0.w);
        r[4] = (short)f2bf(a1.x); r[5] = (short)f2bf(a1.y);
        r[6] = (short)f2bf(a1.z); r[7] = (short)f2bf(a1.w);
        accBn = __builtin_amdgcn_mfma_f32_32x32x16_bf16(r, LWX(j), accBn, 0, 0, 0);
      }
    }
    if (tid < B_) m_lds[((t + 1) & 1) * B_ + tid] = tm[tid * T_ + nxt];

    if (bid != 0 && wid == 0) {
      while (__hip_atomic_load(gen, __ATOMIC_RELAXED, __HIP_MEMORY_SCOPE_AGENT) < tgt)
        __builtin_amdgcn_s_sleep(1);
    }
    __syncthreads();  // (E)
    __builtin_amdgcn_sched_barrier(0);  // no hoisting above the wait

    accB = accBn;
  }

  // finals: hn, cn
  out[(size_t)B_ * T_ * H_ + (size_t)cb * H_ + hu] = hv;
  out[(size_t)B_ * T_ * H_ + (size_t)B_ * H_ + (size_t)cb * H_ + hu] = ccell;
}

extern "C" void kernel_launch(void* const* d_in, const int* in_sizes, int n_in,
                              void* d_out, int out_size, void* d_ws, size_t ws_size,
                              hipStream_t stream) {
  const float* x  = (const float*)d_in[0];
  const float* tm = (const float*)d_in[1];
  const float* Wx = (const float*)d_in[2];
  const float* bx = (const float*)d_in[3];
  const float* Wh = (const float*)d_in[4];
  const float* bh = (const float*)d_in[5];
  float* out = (float*)d_out;
  char* ws = (char*)d_ws;

  unsigned* flags      = (unsigned*)ws;
  unsigned* gen        = (unsigned*)(ws + 2048);
  unsigned short* hrot = (unsigned short*)(ws + WS_HROT);

  const size_t need_rot = (size_t)WS_HROT + (size_t)T_ * HSLOT * 2;
  // zero flags + gen + h slot 0 (h(0) = 0)
  hipMemsetAsync(ws, 0, WS_HROT + HSLOT * 2, stream);
  if (ws_size >= need_rot) {
    lstm_persist<1><<<dim3(NBLK), dim3(NTHR), SMEM_BYTES, stream>>>(
        x, tm, Wx, bx, Wh, bh, out, hrot, flags, gen);
  } else {
    lstm_persist<0><<<dim3(NBLK), dim3(NTHR), SMEM_BYTES, stream>>>(
        x, tm, Wx, bx, Wh, bh, out, hrot, flags, gen);
  }
}

// Round 10
// 5634.157 us; speedup vs baseline: 1.6047x; 1.6047x over previous
//
#include <hip/hip_runtime.h>
#include <stdint.h>

// Teacher-forced LSTM, B=64 T=512 D=H=1024.
// a(t) = m(t)*h(t-1) + (1-m(t))*x(t)   (computed in prev step's cell phase)
// gates(t) = [a(t) | h(t-1)] @ [Wx | Wh]^T + bias   -- one K=2048 GEMM
// Persistent: 128 blocks x 512 thr; block owns 8 hidden units (32 gate rows).
// Weights bf16 LDS-stationary, conflict-free layout [kq][j][kg][n][16B].
// 32x32x16 MFMA; 8 waves = 2 M-tiles(32 batches) x 4 K-quarters(512 k).
// Panel exchange abuf[slot][b][k] bf16 (256KB/slot):
//   ROT=1: slot = t (rotating, never reused). Producers: agent write-through
//   stores. Consumers: PLAIN CACHED loads -> 16 blocks/XCD share one L3->L2
//   fill (the 32MB/step L3 broadcast becomes ~2MB L3 + L2 hits). Safe: each
//   address written once per launch, read only after the flag; one acquire-
//   agent fence at kernel start flushes poison/stale lines (validated R9).
//   ROT=0 fallback (ws too small): 2 slots + agent atomic loads (R5-proven).
// Barrier: per-block flag -> block-0 master polls -> single gen word (R5).

#define B_ 64
#define T_ 512
#define D_ 1024
#define H_ 1024
#define NBLK 128
#define UPB 8
#define NROW 32
#define NTHR 512

typedef __attribute__((ext_vector_type(8))) short short8;
typedef __attribute__((ext_vector_type(16))) float f32x16;

// LDS (bytes): W 131072 @0 | gbuf float[2][64][33] @131072 | bias @147968
#define GBUF_OFF 131072
#define BIAS_OFF 147968
#define SMEM_BYTES 148096

// ws (bytes): flags[128] u32 @0 | gen u32 @2048 | abuf @4096:
//   ROT=1: [512][64 b][2048 k] bf16 (128MB)   ROT=0: [2][64][2048] bf16
#define WS_ABUF 4096
#define PANEL (64 * 2048) /* shorts per slot (256KB) */

__device__ __forceinline__ unsigned f2bf(float f) {  // fp32 -> bf16 RNE
  unsigned u = __float_as_uint(f);
  return (u + 0x7FFFu + ((u >> 16) & 1u)) >> 16;
}
__device__ __forceinline__ float sigf(float x) { return 1.0f / (1.0f + __expf(-x)); }
__device__ __forceinline__ float tanhf_(float x) { return 1.0f - 2.0f / (__expf(2.0f * x) + 1.0f); }

// a(0) = (1-m(0))*x(0) at k=0..1023 of slot 0; h(0)=0 (k=1024..2047) from memset.
__global__ void prep_a0(const float* __restrict__ x, const float* __restrict__ tm,
                        unsigned short* __restrict__ abuf) {
  int i = blockIdx.x * blockDim.x + threadIdx.x;  // over B_*D_
  if (i >= B_ * D_) return;
  int d = i & (D_ - 1), b = i >> 10;
  float m = tm[b * T_];
  float a = (1.0f - m) * x[(size_t)b * T_ * D_ + d];
  abuf[b * 2048 + d] = (unsigned short)f2bf(a);
}

template<int ROT>
__global__ __launch_bounds__(NTHR, 1)
void lstm_persist(const float* __restrict__ xf,
                  const float* __restrict__ tm,
                  const float* __restrict__ Wx, const float* __restrict__ bxp,
                  const float* __restrict__ Wh, const float* __restrict__ bhp,
                  float* __restrict__ out,
                  unsigned short* __restrict__ abuf,
                  unsigned* __restrict__ flags,
                  unsigned* __restrict__ gen)
{
  extern __shared__ char smem[];
  float* gbuf     = (float*)(smem + GBUF_OFF);  // [2][64][33]
  float* bias_lds = (float*)(smem + BIAS_OFF);

  const int tid = threadIdx.x;
  const int bid = blockIdx.x;

  // ---- stage weights -> LDS, conflict-free layout ----
  // dword slot s (0..32767): dw=s&3, n=(s>>2)&31, kg=(s>>7)&1, j=(s>>8)&31, kq=s>>13
  // byte addr = kq*32768 + j*1024 + kg*512 + n*16 + dw*4
  // source: gate-row n -> grow=(n>>3)*H + bid*8 + (n&7); k = kq*512+j*16+kg*8+dw*2
  for (int i = 0; i < 64; ++i) {
    const int s  = i * NTHR + tid;
    const int dw = s & 3, n = (s >> 2) & 31, kgs = (s >> 7) & 1;
    const int js = (s >> 8) & 31, kqs = s >> 13;
    const int grow = (n >> 3) * H_ + bid * UPB + (n & 7);
    const int k = kqs * 512 + js * 16 + kgs * 8 + dw * 2;
    const float* src = (k < D_) ? (Wx + (size_t)grow * D_ + k)
                                : (Wh + (size_t)grow * H_ + (k - D_));
    float2 v = *(const float2*)src;
    *(unsigned*)(smem + (size_t)s * 4) = f2bf(v.x) | (f2bf(v.y) << 16);
  }
  if (tid < NROW) {
    const int grow = (tid >> 3) * H_ + bid * UPB + (tid & 7);
    bias_lds[tid] = bxp[grow] + bhp[grow];
  }

  const int lane = tid & 63;
  const int wid  = tid >> 6;   // 0..7
  const int mt   = wid >> 2;   // M-tile (32 batch rows)
  const int kq   = wid & 3;    // K-quarter of 2048 (512 each)
  const int l31  = lane & 31;  // A: batch row / B: gate row
  const int kg   = lane >> 5;  // 0..1
  const int m0   = mt * 32;

  // weight LDS per-lane base: kq*32768 + kg*512 + l31*16 (+ j*1024)
  const unsigned wbase = (unsigned)(kq * 32768 + kg * 512 + l31 * 16);
#define LDW(J) (*(const short8*)(smem + wbase + (unsigned)((J) * 1024)))
  // A per-lane base (shorts) inside a slot: (m0+l31)*2048 + kq*512 + kg*8 (+ j*16)
  const size_t abase = (size_t)(m0 + l31) * 2048 + (unsigned)(kq * 512 + kg * 8);

  const int cb = tid >> 3;       // cell: batch (0..63)
  const int cu = tid & 7;        // cell: unit within block
  const int hu = bid * UPB + cu; // global hidden unit
  float ccell = 0.0f, hv = 0.0f;

  __syncthreads();
  // one-time L1/L2 invalidate: flush harness poison / prior-launch lines so
  // plain cached reads of abuf are fresh-by-first-touch (validated in R9).
  if (ROT) __builtin_amdgcn_fence(__ATOMIC_ACQUIRE, "agent");

  for (int t = 0; t < T_; ++t) {
    const int nxt = (t + 1 < T_) ? (t + 1) : t;
    const unsigned tgt = (unsigned)(t + 1);

    // ---- A-frags: 32 x 16B from slot t ----
    const unsigned short* hp =
        abuf + (size_t)(ROT ? t : (t & 1)) * PANEL + abase;
    short8 af[32];
    if (ROT) {
#pragma unroll
      for (int j = 0; j < 32; ++j) af[j] = *(const short8*)(hp + j * 16);
    } else {
#pragma unroll
      for (int j = 0; j < 32; ++j) {
        unsigned long long lo = __hip_atomic_load(
            (const unsigned long long*)hp + j * 2,
            __ATOMIC_RELAXED, __HIP_MEMORY_SCOPE_AGENT);
        unsigned long long hi = __hip_atomic_load(
            (const unsigned long long*)hp + j * 2 + 1,
            __ATOMIC_RELAXED, __HIP_MEMORY_SCOPE_AGENT);
        ((unsigned long long*)&af[j])[0] = lo;
        ((unsigned long long*)&af[j])[1] = hi;
      }
    }

    f32x16 acc = {0,0,0,0,0,0,0,0,0,0,0,0,0,0,0,0};
#pragma unroll
    for (int j = 0; j < 32; ++j)
      acc = __builtin_amdgcn_mfma_f32_32x32x16_bf16(af[j], LDW(j), acc, 0, 0, 0);

    // ---- cell operands for t+1 (plain cached; overlap epilogue) ----
    const float mv = tm[cb * T_ + nxt];
    const float xv = xf[((size_t)cb * T_ + nxt) * D_ + hu];

    // ---- cross-kq reduce: kq even writes slab, kq odd adds ----
    // C layout (32x32): col = lane&31, row = (e&3) + 8*(e>>2) + 4*(lane>>5)
    const int s = kq >> 1;
    if ((kq & 1) == 0) {
#pragma unroll
      for (int e = 0; e < 16; ++e) {
        const int br = m0 + (e & 3) + 8 * (e >> 2) + 4 * kg;
        float g = acc[e];
        if (kq == 0) g += bias_lds[l31];
        gbuf[(s * 64 + br) * 33 + l31] = g;
      }
    }
    __syncthreads();  // (B)
    if (kq & 1) {
#pragma unroll
      for (int e = 0; e < 16; ++e) {
        const int br = m0 + (e & 3) + 8 * (e >> 2) + 4 * kg;
        gbuf[(s * 64 + br) * 33 + l31] += acc[e];
      }
    }
    __syncthreads();  // (C)

    // ---- cell: one (b,u) per thread ----
    {
      const float* g0 = gbuf + cb * 33;
      const float* g1 = gbuf + (64 + cb) * 33;
      const float gi = g0[cu]      + g1[cu];
      const float gf = g0[8 + cu]  + g1[8 + cu];
      const float gg = g0[16 + cu] + g1[16 + cu];
      const float go = g0[24 + cu] + g1[24 + cu];
      const float iv = sigf(gi), fv = sigf(gf), gv = tanhf_(gg), ov = sigf(go);
      ccell = ccell * fv + iv * gv;
      hv = ov * tanhf_(ccell);

      if (!ROT || (t + 1 < T_)) {
        const float av = mv * hv + (1.0f - mv) * xv;  // a(t+1) for (cb, hu)
        unsigned short* dst = abuf +
            (size_t)(ROT ? (t + 1) : ((t + 1) & 1)) * PANEL + cb * 2048;
        __hip_atomic_store(dst + hu, (unsigned short)f2bf(av),
                           __ATOMIC_RELAXED, __HIP_MEMORY_SCOPE_AGENT);
        __hip_atomic_store(dst + 1024 + hu, (unsigned short)f2bf(hv),
                           __ATOMIC_RELAXED, __HIP_MEMORY_SCOPE_AGENT);
      }
    }

    __syncthreads();  // (D) drains a/h stores (vmcnt(0) before s_barrier)

    if (bid == 0) {
      if (wid == 0) {
        const int i0 = 1 + lane;   // 1..64
        const int i1 = 65 + lane;  // 65..127 valid
        for (;;) {
          unsigned v0 = __hip_atomic_load(flags + i0,
                                          __ATOMIC_RELAXED, __HIP_MEMORY_SCOPE_AGENT);
          unsigned v1 = (i1 < NBLK)
                          ? __hip_atomic_load(flags + i1,
                                              __ATOMIC_RELAXED, __HIP_MEMORY_SCOPE_AGENT)
                          : tgt;
          if (__all((v0 >= tgt) && (v1 >= tgt))) break;
          __builtin_amdgcn_s_sleep(1);
        }
        if (lane == 0)
          __hip_atomic_store(gen, tgt, __ATOMIC_RELAXED, __HIP_MEMORY_SCOPE_AGENT);
      }
      out[((size_t)cb * T_ + t) * H_ + hu] = hv;  // off critical path
    } else {
      if (tid == 0)
        __hip_atomic_store(flags + bid, tgt,
                           __ATOMIC_RELAXED, __HIP_MEMORY_SCOPE_AGENT);
      out[((size_t)cb * T_ + t) * H_ + hu] = hv;  // overlaps gen wait
      if (wid == 0) {
        while (__hip_atomic_load(gen, __ATOMIC_RELAXED, __HIP_MEMORY_SCOPE_AGENT) < tgt)
          __builtin_amdgcn_s_sleep(1);
      }
    }
    __syncthreads();  // (E)
    __builtin_amdgcn_sched_barrier(0);  // nothing hoists above the wait
  }

  // finals: hn, cn
  out[(size_t)B_ * T_ * H_ + (size_t)cb * H_ + hu] = hv;
  out[(size_t)B_ * T_ * H_ + (size_t)B_ * H_ + (size_t)cb * H_ + hu] = ccell;
}

extern "C" void kernel_launch(void* const* d_in, const int* in_sizes, int n_in,
                              void* d_out, int out_size, void* d_ws, size_t ws_size,
                              hipStream_t stream) {
  const float* x  = (const float*)d_in[0];
  const float* tm = (const float*)d_in[1];
  const float* Wx = (const float*)d_in[2];
  const float* bx = (const float*)d_in[3];
  const float* Wh = (const float*)d_in[4];
  const float* bh = (const float*)d_in[5];
  float* out = (float*)d_out;
  char* ws = (char*)d_ws;

  unsigned* flags      = (unsigned*)ws;
  unsigned* gen        = (unsigned*)(ws + 2048);
  unsigned short* abuf = (unsigned short*)(ws + WS_ABUF);

  const size_t need_rot = (size_t)WS_ABUF + (size_t)T_ * PANEL * 2;
  // zero flags + gen + slot 0 (a(0) overwritten by prep_a0; h(0)=0 stays)
  hipMemsetAsync(ws, 0, WS_ABUF + PANEL * 2, stream);
  prep_a0<<<dim3((B_ * D_ + 255) / 256), dim3(256), 0, stream>>>(x, tm, abuf);
  if (ws_size >= need_rot) {
    lstm_persist<1><<<dim3(NBLK), dim3(NTHR), SMEM_BYTES, stream>>>(
        x, tm, Wx, bx, Wh, bh, out, abuf, flags, gen);
  } else {
    lstm_persist<0><<<dim3(NBLK), dim3(NTHR), SMEM_BYTES, stream>>>(
        x, tm, Wx, bx, Wh, bh, out, abuf, flags, gen);
  }
}

// Round 11
// 2721.685 us; speedup vs baseline: 3.3219x; 2.0701x over previous
//
#include <hip/hip_runtime.h>
#include <stdint.h>

// Teacher-forced LSTM, B=64 T=512 D=H=1024.
// a(t) = m(t)*h(t-1) + (1-m(t))*x(t)   (computed in prev step's cell phase)
// gates(t) = [a(t) | h(t-1)] @ [Wx | Wh]^T + bias   -- one K=2048 GEMM
// Persistent: 256 blocks x 512 thr = 128 unit-groups x 2 batch-halves.
// Block (ug,bg): 32 batches (bg*32..) x 8 units (ug*8.., 32 gate rows).
// Panel per block = 128 KB (half of R5) -- the per-CU panel-BW lever.
// Weights bf16 128KB LDS-stationary, conflict-free layout [ko][j][kg][n][16B].
// 32x32x16 MFMA; 8 waves = 8 K-eighths (256 k each); 2-phase 4-slab reduce.
// Panel abuf[2 slot][256 kblk][64 b][8] bf16 (R5's coalesced layout).
// Producers: agent write-through stores. Consumers: agent atomic 8B loads
// (compiler-pipelined; R5-proven). Barrier: per-block flag -> block-0 master
// polls 256 -> single gen word. No cache-wide fences.

#define B_ 64
#define T_ 512
#define D_ 1024
#define H_ 1024
#define NBLK 256
#define UPB 8
#define NROW 32
#define NTHR 512

typedef __attribute__((ext_vector_type(8))) short short8;
typedef __attribute__((ext_vector_type(16))) float f32x16;

// LDS (bytes): W 131072 @0 | gbuf float[4][32][33] @131072 | bias @147968
#define GBUF_OFF 131072
#define BIAS_OFF 147968
#define SMEM_BYTES 148096

// ws (bytes): flags[256] u32 @0 | gen u32 @2048 | abuf @4096:
//   [2][256 kblk][64 b][8] bf16  (256KB per slot)
#define WS_ABUF 4096
#define PANEL (64 * 2048) /* shorts per slot */

__device__ __forceinline__ unsigned f2bf(float f) {  // fp32 -> bf16 RNE
  unsigned u = __float_as_uint(f);
  return (u + 0x7FFFu + ((u >> 16) & 1u)) >> 16;
}
__device__ __forceinline__ float sigf(float x) { return 1.0f / (1.0f + __expf(-x)); }
__device__ __forceinline__ float tanhf_(float x) { return 1.0f - 2.0f / (__expf(2.0f * x) + 1.0f); }

// a(0) = (1-m(0))*x(0) at k<1024 of slot 0; h(0)=0 (k>=1024) from memset.
__global__ void prep_a0(const float* __restrict__ x, const float* __restrict__ tm,
                        unsigned short* __restrict__ abuf) {
  int i = blockIdx.x * blockDim.x + threadIdx.x;  // over B_*D_
  if (i >= B_ * D_) return;
  int d = i & (D_ - 1), b = i >> 10;
  float m = tm[b * T_];
  float a = (1.0f - m) * x[(size_t)b * T_ * D_ + d];
  abuf[((d >> 3) * 64 + b) * 8 + (d & 7)] = (unsigned short)f2bf(a);
}

__global__ __launch_bounds__(NTHR, 1)
void lstm_persist(const float* __restrict__ xf,
                  const float* __restrict__ tm,
                  const float* __restrict__ Wx, const float* __restrict__ bxp,
                  const float* __restrict__ Wh, const float* __restrict__ bhp,
                  float* __restrict__ out,
                  unsigned short* __restrict__ abuf,
                  unsigned* __restrict__ flags,
                  unsigned* __restrict__ gen)
{
  extern __shared__ char smem[];
  float* gbuf     = (float*)(smem + GBUF_OFF);  // [4][32][33]
  float* bias_lds = (float*)(smem + BIAS_OFF);

  const int tid = threadIdx.x;
  const int bid = blockIdx.x;
  const int ug  = bid >> 1;   // unit group 0..127 (units ug*8..+7)
  const int bg  = bid & 1;    // batch half 0..1 (batches bg*32..+31)

  // ---- stage weights -> LDS, conflict-free layout ----
  // dword s (0..32767): dw=s&3, n=(s>>2)&31, kg=(s>>7)&1, j=(s>>8)&15, ko=s>>12
  // byte = ko*16384 + j*1024 + kg*512 + n*16 + dw*4
  // k = ko*256 + j*16 + kg*8 + dw*2 ; gate-row n -> grow=(n>>3)*H + ug*8 + (n&7)
  for (int i = 0; i < 64; ++i) {
    const int s  = i * NTHR + tid;
    const int dw = s & 3, n = (s >> 2) & 31, kgs = (s >> 7) & 1;
    const int js = (s >> 8) & 15, kos = s >> 12;
    const int grow = (n >> 3) * H_ + ug * UPB + (n & 7);
    const int k = kos * 256 + js * 16 + kgs * 8 + dw * 2;
    const float* src = (k < D_) ? (Wx + (size_t)grow * D_ + k)
                                : (Wh + (size_t)grow * H_ + (k - D_));
    float2 v = *(const float2*)src;
    *(unsigned*)(smem + (size_t)s * 4) = f2bf(v.x) | (f2bf(v.y) << 16);
  }
  if (tid < NROW) {
    const int grow = (tid >> 3) * H_ + ug * UPB + (tid & 7);
    bias_lds[tid] = bxp[grow] + bhp[grow];
  }

  const int lane = tid & 63;
  const int wid  = tid >> 6;   // 0..7 = K-eighth (256 k)
  const int ko   = wid;
  const int l31  = lane & 31;  // A: batch row in half / B: gate row
  const int kg   = lane >> 5;  // 0..1
  const int b0   = bg * 32;

  // weight LDS per-lane base: ko*16384 + kg*512 + l31*16 (+ j*1024)
  const unsigned wbase = (unsigned)(ko * 16384 + kg * 512 + l31 * 16);
#define LDW(J) (*(const short8*)(smem + wbase + (unsigned)((J) * 1024)))
  // A-frag j: kblk = ko*32 + j*2 + kg, batch = b0+l31
  // ull index = (kblk*64 + batch)*2  -> base + j*256
  const size_t aull0 = ((size_t)(ko * 32 + kg) * 64 + (b0 + l31)) * 2;

  const int act = (tid < 256);
  const int cb2 = (tid >> 3) & 31;   // batch within half
  const int cu  = tid & 7;           // unit within group
  const int b   = b0 + cb2;          // global batch
  const int hu  = ug * UPB + cu;     // global hidden unit
  float ccell = 0.0f, hv = 0.0f;

  unsigned cur = 0;
  __syncthreads();

  for (int t = 0; t < T_; ++t) {
    const int nxt = (t + 1 < T_) ? (t + 1) : t;
    const unsigned tgt = (unsigned)(t + 1);

    // ---- A-frags: 16 x 16B via 32 agent-scope 8B loads (coalesced layout) ----
    const unsigned long long* ap =
        (const unsigned long long*)(abuf + (size_t)cur * PANEL) + aull0;
    short8 af[16];
#pragma unroll
    for (int j = 0; j < 16; ++j) {
      unsigned long long lo = __hip_atomic_load(ap + (size_t)j * 256,
                                                __ATOMIC_RELAXED, __HIP_MEMORY_SCOPE_AGENT);
      unsigned long long hi = __hip_atomic_load(ap + (size_t)j * 256 + 1,
                                                __ATOMIC_RELAXED, __HIP_MEMORY_SCOPE_AGENT);
      ((unsigned long long*)&af[j])[0] = lo;
      ((unsigned long long*)&af[j])[1] = hi;
    }

    f32x16 acc = {0,0,0,0,0,0,0,0,0,0,0,0,0,0,0,0};
#pragma unroll
    for (int j = 0; j < 16; ++j)
      acc = __builtin_amdgcn_mfma_f32_32x32x16_bf16(af[j], LDW(j), acc, 0, 0, 0);

    // ---- cell operands for t+1 (plain cached; overlap epilogue) ----
    float mv = 0.0f, xv = 0.0f;
    if (act) {
      mv = tm[b * T_ + nxt];
      xv = xf[((size_t)b * T_ + nxt) * D_ + hu];
    }

    // ---- 8-way K reduce: waves 0-3 write slab wid, waves 4-7 add slab wid-4 ----
    // C layout (32x32): col = lane&31 (gate row), row = (e&3)+8*(e>>2)+4*kg (batch)
    const int s = wid & 3;
    if (wid < 4) {
#pragma unroll
      for (int e = 0; e < 16; ++e) {
        const int br = (e & 3) + 8 * (e >> 2) + 4 * kg;
        float g = acc[e];
        if (wid == 0) g += bias_lds[l31];
        gbuf[(s * 32 + br) * 33 + l31] = g;
      }
    }
    __syncthreads();  // (B)
    if (wid >= 4) {
#pragma unroll
      for (int e = 0; e < 16; ++e) {
        const int br = (e & 3) + 8 * (e >> 2) + 4 * kg;
        gbuf[(s * 32 + br) * 33 + l31] += acc[e];
      }
    }
    __syncthreads();  // (C)

    // ---- cell: one (b,u) per thread (tid<256) ----
    if (act) {
      float gi = 0.0f, gf = 0.0f, gg = 0.0f, go = 0.0f;
#pragma unroll
      for (int sl = 0; sl < 4; ++sl) {
        const float* row = gbuf + (sl * 32 + cb2) * 33;
        gi += row[cu];      gf += row[8 + cu];
        gg += row[16 + cu]; go += row[24 + cu];
      }
      const float iv = sigf(gi), fv = sigf(gf), gv = tanhf_(gg), ov = sigf(go);
      ccell = ccell * fv + iv * gv;
      hv = ov * tanhf_(ccell);

      const float av = mv * hv + (1.0f - mv) * xv;  // a(t+1) for (b, hu)
      unsigned short* dst = abuf + (size_t)(cur ^ 1u) * PANEL;
      // a at k=hu ; h at k=1024+hu  (layout [kblk][b][8])
      __hip_atomic_store(dst + (((hu >> 3) * 64) + b) * 8 + (hu & 7),
                         (unsigned short)f2bf(av),
                         __ATOMIC_RELAXED, __HIP_MEMORY_SCOPE_AGENT);
      __hip_atomic_store(dst + ((((1024 + hu) >> 3) * 64) + b) * 8 + (hu & 7),
                         (unsigned short)f2bf(hv),
                         __ATOMIC_RELAXED, __HIP_MEMORY_SCOPE_AGENT);
    }

    __syncthreads();  // (D) drains a/h stores (vmcnt(0) before s_barrier)

    if (bid == 0) {
      if (wid == 0) {
        for (;;) {
          unsigned v0 = (lane == 0) ? tgt
              : __hip_atomic_load(flags + lane, __ATOMIC_RELAXED, __HIP_MEMORY_SCOPE_AGENT);
          unsigned v1 = __hip_atomic_load(flags + 64 + lane,
                                          __ATOMIC_RELAXED, __HIP_MEMORY_SCOPE_AGENT);
          unsigned v2 = __hip_atomic_load(flags + 128 + lane,
                                          __ATOMIC_RELAXED, __HIP_MEMORY_SCOPE_AGENT);
          unsigned v3 = __hip_atomic_load(flags + 192 + lane,
                                          __ATOMIC_RELAXED, __HIP_MEMORY_SCOPE_AGENT);
          if (__all((v0 >= tgt) && (v1 >= tgt) && (v2 >= tgt) && (v3 >= tgt))) break;
          __builtin_amdgcn_s_sleep(1);
        }
        if (lane == 0)
          __hip_atomic_store(gen, tgt, __ATOMIC_RELAXED, __HIP_MEMORY_SCOPE_AGENT);
      }
      if (act) out[((size_t)b * T_ + t) * H_ + hu] = hv;  // off critical path
    } else {
      if (tid == 0)
        __hip_atomic_store(flags + bid, tgt,
                           __ATOMIC_RELAXED, __HIP_MEMORY_SCOPE_AGENT);
      if (act) out[((size_t)b * T_ + t) * H_ + hu] = hv;  // overlaps gen wait
      if (wid == 0) {
        while (__hip_atomic_load(gen, __ATOMIC_RELAXED, __HIP_MEMORY_SCOPE_AGENT) < tgt)
          __builtin_amdgcn_s_sleep(1);
      }
    }
    __syncthreads();  // (E)
    __builtin_amdgcn_sched_barrier(0);  // nothing hoists above the wait

    cur ^= 1u;
  }

  // finals: hn, cn
  if (act) {
    out[(size_t)B_ * T_ * H_ + (size_t)b * H_ + hu] = hv;
    out[(size_t)B_ * T_ * H_ + (size_t)B_ * H_ + (size_t)b * H_ + hu] = ccell;
  }
}

extern "C" void kernel_launch(void* const* d_in, const int* in_sizes, int n_in,
                              void* d_out, int out_size, void* d_ws, size_t ws_size,
                              hipStream_t stream) {
  const float* x  = (const float*)d_in[0];
  const float* tm = (const float*)d_in[1];
  const float* Wx = (const float*)d_in[2];
  const float* bx = (const float*)d_in[3];
  const float* Wh = (const float*)d_in[4];
  const float* bh = (const float*)d_in[5];
  float* out = (float*)d_out;
  char* ws = (char*)d_ws;

  unsigned* flags      = (unsigned*)ws;
  unsigned* gen        = (unsigned*)(ws + 2048);
  unsigned short* abuf = (unsigned short*)(ws + WS_ABUF);

  // zero flags + gen + both slots (h(0)=0 comes from this)
  hipMemsetAsync(ws, 0, WS_ABUF + 2 * PANEL * 2, stream);
  prep_a0<<<dim3((B_ * D_ + 255) / 256), dim3(256), 0, stream>>>(x, tm, abuf);
  lstm_persist<<<dim3(NBLK), dim3(NTHR), SMEM_BYTES, stream>>>(
      x, tm, Wx, bx, Wh, bh, out, abuf, flags, gen);
}